// Round 7
// baseline (167.783 us; speedup 1.0000x reference)
//
#include <hip/hip_runtime.h>
#include <hip/hip_bf16.h>
#include <math.h>

// ---------------------------------------------------------------------------
// Q_Mlp: x0 -> int4-quant -> GEMM1(K=768) -> dequant+GELU+clip -> int4-quant
//        -> GEMM2(K=3072) -> dequant+bias -> out (f32)
// Quantized operands are integers in [-8,7]: exact in int8. i8 MFMA
// (16x16x64, 2x bf16 rate) with i32 accumulation (max |acc| < 2^18, exact).
//
// Attribution (r6): GEMM1 = 78.6us bottleneck; GEMM2 = ~43us. r5 decomposition
// shows GEMM1 @ LB=5 ran 57.7us (5 blocks/CU, 5 waves/SIMD) -> keep LB=5.
//
// K-permutation trick (this round): a GEMM is invariant under any permutation
// of k applied to BOTH operands. hq is stored with phys byte = g*64 + c*4 + n
// for logical col g*64 + n*16 + c  (g = 64-col group, n = 0..3, c = 0..15).
// GEMM1's epilogue thus packs its 4 per-row bytes (logical cols c+{0,16,32,48})
// into ONE dword store (16 dword-stores/thread instead of 64 byte-stores,
// dense 64B segments). quant_w2 applies the SAME permutation to wq2's k-dim,
// so GEMM2 reads A and B in consistent phys order -> identical result.
//
// LDS bank-conflict fix (T2, rule #21 both-sides involution), verified 1.4e7->0:
//   col ^= ((row&7)<<4); staging pre-swizzles the GLOBAL source col
//   (global_load_lds dest stays linear); fragment read applies the same XOR.
//
// Workspace layout (bytes):
//   [0,256)              : a1, a2, inv_a2, 0.5*inv_a2 (f32)
//   [256, +12582912)     : xq  i8 [16384][768]
//   [12583168, +2359296) : wq1 i8 [3072][768]
//   [14942464, +2359296) : wq2 i8 [768][3072]  (k-permuted)
//   [17301760, +50331648): hq  i8 [16384][3072] (k-permuted)
// ---------------------------------------------------------------------------

typedef __attribute__((ext_vector_type(4))) int i32x4;

__device__ __forceinline__ void gload_lds16(const void* g, void* l) {
  __builtin_amdgcn_global_load_lds(
      (const __attribute__((address_space(1))) void*)g,
      (__attribute__((address_space(3))) void*)l, 16, 0, 0);
}

// quantize: round-half-even(clip(x/a, -8, 7)) -> int in [-8,7]
__device__ __forceinline__ int q4_i8(float x, float a) {
  float t = x / a;  // IEEE div, matches numpy
  t = fminf(fmaxf(t, -8.0f), 7.0f);
  t = rintf(t);  // RNE, matches np.round
  return (int)t;
}

// ---- means of alpha_a1 (768) and alpha_a2 (3072), f64 accumulate ----------
__global__ void means_k(const float* __restrict__ v1, int n1,
                        const float* __restrict__ v2, int n2,
                        float* __restrict__ out) {
  const float* src = blockIdx.x ? v2 : v1;
  const int n = blockIdx.x ? n2 : n1;
  __shared__ double red[256];
  double s = 0.0;
  for (int i = threadIdx.x; i < n; i += 256) s += (double)src[i];
  red[threadIdx.x] = s;
  __syncthreads();
  for (int st = 128; st > 0; st >>= 1) {
    if (threadIdx.x < st) red[threadIdx.x] += red[threadIdx.x + st];
    __syncthreads();
  }
  if (threadIdx.x == 0) {
    float m = (float)(red[0] / (double)n);
    out[blockIdx.x] = m;
    if (blockIdx.x == 1) {
      out[2] = 1.0f / m;
      out[3] = 0.5f * (1.0f / m);
    }
  }
}

// ---- quantize activations x0 -> xq i8 -------------------------------------
__global__ void quant_x_k(const float* __restrict__ x,
                          unsigned* __restrict__ xq,
                          const float* __restrict__ means, int n4) {
  int i = blockIdx.x * blockDim.x + threadIdx.x;
  if (i >= n4) return;
  const float a = means[0];
  float4 v = ((const float4*)x)[i];
  unsigned u = (q4_i8(v.x, a) & 0xFF) | ((q4_i8(v.y, a) & 0xFF) << 8) |
               ((q4_i8(v.z, a) & 0xFF) << 16) | ((q4_i8(v.w, a) & 0xFF) << 24);
  xq[i] = u;
}

// ---- quantize weights w1 [R][C] natural order, per-row alpha --------------
__global__ void quant_w_k(const float* __restrict__ w,
                          const float* __restrict__ alpha,
                          unsigned* __restrict__ wq, int C, int n4) {
  int i = blockIdx.x * blockDim.x + threadIdx.x;
  if (i >= n4) return;
  int row = (i * 4) / C;
  const float a = alpha[row];
  float4 v = ((const float4*)w)[i];
  unsigned u = (q4_i8(v.x, a) & 0xFF) | ((q4_i8(v.y, a) & 0xFF) << 8) |
               ((q4_i8(v.z, a) & 0xFF) << 16) | ((q4_i8(v.w, a) & 0xFF) << 24);
  wq[i] = u;
}

// ---- quantize w2 [768][3072] with k-PERMUTED layout -----------------------
// phys dword p in row: g = p>>4, c = p&15; packs logical cols g*64 + n*16 + c
// for n = 0..3 (byte n of the dword). Matches GEMM1's hq write permutation.
__global__ void quant_w2_k(const float* __restrict__ w,
                           const float* __restrict__ alpha,
                           unsigned* __restrict__ wq, int nd) {
  int i = blockIdx.x * blockDim.x + threadIdx.x;
  if (i >= nd) return;  // nd = 768*768 dwords
  const int row = i / 768;
  const int p = i - row * 768;
  const int g = p >> 4, c = p & 15;
  const float a = alpha[row];
  const float* src = w + (size_t)row * 3072 + g * 64 + c;
  unsigned d = 0;
#pragma unroll
  for (int n = 0; n < 4; ++n)
    d |= ((unsigned)(q4_i8(src[n * 16], a) & 0xFF)) << (8 * n);
  wq[i] = d;
}

// ---- GEMM1: C = A[M,K] * B[N,K]^T, 256t, 128x128 tile, BK=128, LB=5 -------
// dequant+bias -> gelu(exact-erf approx) -> quant(a2) -> packed-dword i8 hq
__global__ __launch_bounds__(256, 5) void gemm1_k(
    const signed char* __restrict__ A, const signed char* __restrict__ B,
    const float* __restrict__ alphaw, const float* __restrict__ bias,
    const float* __restrict__ means, unsigned* __restrict__ out_u, int N,
    int K) {
  __shared__ __align__(16) signed char sA[128 * 128];
  __shared__ __align__(16) signed char sB[128 * 128];
  const int tid = threadIdx.x;
  const int w = tid >> 6;
  const int l = tid & 63;
  const int wm = w >> 1, wn = w & 1;
  const long bm0 = (long)blockIdx.y * 128;
  const long bn0 = (long)blockIdx.x * 128;

  i32x4 acc[4][4] = {};

  const int srow = l >> 3;                        // row-within-chunk 0..7
  const int scol = ((l & 7) * 16) ^ (srow << 4);  // pre-swizzled src col
  const int rsw = (l & 7) << 4;                   // read-side XOR

  for (int kt = 0; kt < K; kt += 128) {
    __syncthreads();  // previous tile's LDS reads done
#pragma unroll
    for (int i = 0; i < 4; ++i) {
      const int c = w * 4 + i;  // chunk: 8 rows = 1KB of LDS
      const int row = c * 8 + srow;
      gload_lds16(A + (bm0 + row) * K + kt + scol, &sA[c * 1024]);
      gload_lds16(B + (bn0 + row) * K + kt + scol, &sB[c * 1024]);
    }
    __syncthreads();  // staging visible (compiler drains vmcnt)
#pragma unroll
    for (int kk = 0; kk < 2; ++kk) {
      const int kc = (kk * 64 + (l >> 4) * 16) ^ rsw;  // swizzled k-col
      i32x4 af[4], bg[4];
#pragma unroll
      for (int m = 0; m < 4; ++m)
        af[m] = *(const i32x4*)&sA[(wm * 64 + m * 16 + (l & 15)) * 128 + kc];
#pragma unroll
      for (int n = 0; n < 4; ++n)
        bg[n] = *(const i32x4*)&sB[(wn * 64 + n * 16 + (l & 15)) * 128 + kc];
#pragma unroll
      for (int m = 0; m < 4; ++m)
#pragma unroll
        for (int n = 0; n < 4; ++n)
          acc[m][n] = __builtin_amdgcn_mfma_i32_16x16x64_i8(af[m], bg[n],
                                                            acc[m][n], 0, 0, 0);
    }
  }

  const float a1 = means[0];
  const float half_inv_a2 = means[3];

  float awa1[4], bsc[4];
  const int cc0 = (int)bn0 + wn * 64 + (l & 15);  // logical col base
#pragma unroll
  for (int n = 0; n < 4; ++n) {
    awa1[n] = alphaw[cc0 + n * 16] * a1;
    bsc[n] = bias[cc0 + n * 16];
  }

  const int r0 = (int)bm0 + wm * 64 + (l >> 4) * 4;
  const int Nd = N >> 2;  // dwords per row (768)
  const int pd = ((int)bn0 >> 2) + wn * 16 + (l & 15);  // phys dword in row

#pragma unroll
  for (int m = 0; m < 4; ++m) {
#pragma unroll
    for (int rg = 0; rg < 4; ++rg) {
      const int r = r0 + m * 16 + rg;
      unsigned d = 0;
#pragma unroll
      for (int n = 0; n < 4; ++n) {
        const float f = (float)acc[m][n][rg];  // exact: |acc| < 2^18
        const float t = fmaf(f, awa1[n], bsc[n]);
        // exact-formula GELU via A&S 7.1.26 erf (|err|<=1.5e-7)
        const float x = t * 0.70710678118654752f;
        const float az = fabsf(x);
        const float rr = __builtin_amdgcn_rcpf(fmaf(0.3275911f, az, 1.0f));
        float p = fmaf(rr, 1.061405429f, -1.453152027f);
        p = fmaf(rr, p, 1.421413741f);
        p = fmaf(rr, p, -0.284496736f);
        p = fmaf(rr, p, 0.254829592f);
        p = p * rr;
        const float e = __expf(-az * az);
        float er = fmaf(-p, e, 1.0f);
        er = copysignf(er, x);
        // +/-10 clip dropped: 10/a2 > 7 always, saturation identical
        float qv = t * (1.0f + er) * half_inv_a2;
        qv = fminf(fmaxf(qv, -8.0f), 7.0f);
        qv = rintf(qv);
        d |= ((unsigned)((int)qv & 0xFF)) << (8 * n);  // phys byte c*4+n
      }
      out_u[(size_t)r * Nd + pd] = d;
    }
  }
}

// ---- GEMM2: C = A[M,K] * B[N,K]^T, 512t / 8 waves, 128x128 tile, BK=128 ---
// A = hq, B = wq2, both k-permuted identically -> dot products unchanged.
// dequant(a2,alpha_w2)+bias -> f32 out (bit-exact numpy chain)
__global__ __launch_bounds__(512, 6) void gemm2_k(
    const signed char* __restrict__ A, const signed char* __restrict__ B,
    const float* __restrict__ alphaw, const float* __restrict__ bias,
    const float* __restrict__ means, float* __restrict__ out_f, int N, int K) {
  __shared__ __align__(16) signed char sA[128 * 128];
  __shared__ __align__(16) signed char sB[128 * 128];
  const int tid = threadIdx.x;
  const int w = tid >> 6;  // 0..7
  const int l = tid & 63;
  const int wm = w >> 1, wn = w & 1;
  const long bm0 = (long)blockIdx.y * 128;
  const long bn0 = (long)blockIdx.x * 128;

  i32x4 acc[2][4] = {};

  const int srow = l >> 3;                        // row-within-chunk 0..7
  const int scol = ((l & 7) * 16) ^ (srow << 4);  // pre-swizzled src col
  const int rsw = (l & 7) << 4;                   // read-side XOR

  const signed char* gA = A + (bm0 + w * 16 + srow) * (long)K + scol;
  const signed char* gB = B + (bn0 + w * 16 + srow) * (long)K + scol;

  for (int kt = 0; kt < K; kt += 128) {
    __syncthreads();  // previous tile's LDS reads done
#pragma unroll
    for (int i = 0; i < 2; ++i) {  // wave stages chunks 2w+i (A and B)
      gload_lds16(gA + (long)i * 8 * K + kt, &sA[(w * 2 + i) * 1024]);
      gload_lds16(gB + (long)i * 8 * K + kt, &sB[(w * 2 + i) * 1024]);
    }
    __syncthreads();  // staging visible (compiler drains vmcnt)
#pragma unroll
    for (int kk = 0; kk < 2; ++kk) {
      const int kc = (kk * 64 + (l >> 4) * 16) ^ rsw;  // swizzled k-col
      i32x4 af[2], bg[4];
#pragma unroll
      for (int m = 0; m < 2; ++m)
        af[m] = *(const i32x4*)&sA[(wm * 32 + m * 16 + (l & 15)) * 128 + kc];
#pragma unroll
      for (int n = 0; n < 4; ++n)
        bg[n] = *(const i32x4*)&sB[(wn * 64 + n * 16 + (l & 15)) * 128 + kc];
#pragma unroll
      for (int m = 0; m < 2; ++m)
#pragma unroll
        for (int n = 0; n < 4; ++n)
          acc[m][n] = __builtin_amdgcn_mfma_i32_16x16x64_i8(af[m], bg[n],
                                                            acc[m][n], 0, 0, 0);
    }
  }

  const float a2 = means[1];

  float awc[4], bsc[4];
  const int cc0 = (int)bn0 + wn * 64 + (l & 15);
#pragma unroll
  for (int n = 0; n < 4; ++n) {
    awc[n] = alphaw[cc0 + n * 16];
    bsc[n] = bias[cc0 + n * 16];
  }

  const int r0 = (int)bm0 + wm * 32 + (l >> 4) * 4;

#pragma unroll
  for (int m = 0; m < 2; ++m) {
#pragma unroll
    for (int rg = 0; rg < 4; ++rg) {
      const int r = r0 + m * 16 + rg;
      float* prow = out_f + (size_t)r * N + cc0;
#pragma unroll
      for (int n = 0; n < 4; ++n) {
        const float f = (float)acc[m][n][rg];
        // bit-exact numpy chain: ((x*aw)*a2) + b, no FMA contraction
        float t = __fmul_rn(f, awc[n]);
        t = __fmul_rn(t, a2);
        t = __fadd_rn(t, bsc[n]);
        prow[n * 16] = t;
      }
    }
  }
}

extern "C" void kernel_launch(void* const* d_in, const int* in_sizes, int n_in,
                              void* d_out, int out_size, void* d_ws,
                              size_t ws_size, hipStream_t stream) {
  const float* x0 = (const float*)d_in[0];
  const float* w1 = (const float*)d_in[1];
  const float* b1 = (const float*)d_in[2];
  const float* aw1 = (const float*)d_in[3];
  const float* aa1 = (const float*)d_in[4];
  const float* w2 = (const float*)d_in[5];
  const float* b2 = (const float*)d_in[6];
  const float* aw2 = (const float*)d_in[7];
  const float* aa2 = (const float*)d_in[8];

  char* ws = (char*)d_ws;
  float* means = (float*)ws;
  signed char* xq = (signed char*)(ws + 256);
  signed char* wq1 = (signed char*)(ws + 12583168);
  signed char* wq2 = (signed char*)(ws + 14942464);
  signed char* hq = (signed char*)(ws + 17301760);

  // 1) means of alpha_a1 / alpha_a2 (+ 1/a2, 0.5/a2)
  means_k<<<2, 256, 0, stream>>>(aa1, 768, aa2, 3072, means);
  // 2) quantize activations and weights to i8 (wq2 k-permuted)
  quant_x_k<<<12288, 256, 0, stream>>>(x0, (unsigned*)xq, means, 3145728);
  quant_w_k<<<2304, 256, 0, stream>>>(w1, aw1, (unsigned*)wq1, 768, 589824);
  quant_w2_k<<<2304, 256, 0, stream>>>(w2, aw2, (unsigned*)wq2, 589824);
  // 3) GEMM1 [16384,768]x[3072,768]^T + gelu + requant -> hq (i8, k-permuted)
  dim3 g1(24, 128);
  gemm1_k<<<g1, 256, 0, stream>>>(xq, wq1, aw1, b1, means, (unsigned*)hq, 3072,
                                  768);
  // 4) GEMM2 [16384,3072]x[768,3072]^T + bias -> f32 out (512 threads)
  dim3 g2(6, 128);
  gemm2_k<<<g2, 512, 0, stream>>>(hq, wq2, aw2, b2, means, (float*)d_out, 768,
                                  3072);
}

// Round 8
// 151.591 us; speedup vs baseline: 1.1068x; 1.1068x over previous
//
#include <hip/hip_runtime.h>
#include <hip/hip_bf16.h>
#include <math.h>

// ---------------------------------------------------------------------------
// Q_Mlp: x0 -> int4-quant -> GEMM1(K=768) -> dequant+GELU+clip -> int4-quant
//        -> GEMM2(K=3072) -> dequant+bias -> out (f32)
// Quantized operands are integers in [-8,7]: exact in int8. i8 MFMA
// (16x16x64, 2x bf16 rate) with i32 accumulation (max |acc| < 2^18, exact).
//
// Ledger (corrected r7): gemm1@256t/LB4 = 78.6us, gemm2@512t = 43us, pre ~15us.
// LB=5 at 256t spills (acc 64 + ~48 VGPR = 112 > 102 budget): WRITE_SIZE
// 49->89MB was spill traffic. 4-wave 128^2 kernel is register-pinned to LB4.
//
// This round: BK=64 DOUBLE-BUFFERED pipeline at 512t for BOTH gemms.
//   - 4 x 8KB LDS buffers = 32KB -> 3 blocks/CU = 6 waves/SIMD (occupancy
//     kept, unlike r4's 64KB dbuf which halved blocks).
//   - STAGE(next tile) issued BEFORE COMPUTE(cur); __syncthreads' vmcnt(0)
//     drain lands ~free (loads had a full compute phase in flight).
//   - acc[2][4] = 32 unified regs/thread -> fits 85-reg budget (r6: 48 VGPR).
//
// BK=64 swizzle (both-sides involution, zero-cost lane-const XOR):
//   LDS row pitch 64B (4 x 16B slots). phys slot s holds logical s^(row&3).
//   stage: source col = ((l&3) ^ ((l>>2)&3))*16 (gload_lds dest stays linear);
//   read:  phys slot = (l>>4) ^ (l&3)  (row&3 == l&3 for all fragments).
//   Gives uniform 8 accesses/bank for a wave b128 read = the b128 floor.
//
// Workspace layout (bytes):
//   [0,256)              : a1, a2, inv_a2, 0.5*inv_a2 (f32)
//   [256, +12582912)     : xq  i8 [16384][768]
//   [12583168, +2359296) : wq1 i8 [3072][768]
//   [14942464, +2359296) : wq2 i8 [768][3072]
//   [17301760, +50331648): hq  i8 [16384][3072]
// ---------------------------------------------------------------------------

typedef __attribute__((ext_vector_type(4))) int i32x4;

__device__ __forceinline__ void gload_lds16(const void* g, void* l) {
  __builtin_amdgcn_global_load_lds(
      (const __attribute__((address_space(1))) void*)g,
      (__attribute__((address_space(3))) void*)l, 16, 0, 0);
}

// quantize: round-half-even(clip(x/a, -8, 7)) -> int in [-8,7]
__device__ __forceinline__ int q4_i8(float x, float a) {
  float t = x / a;  // IEEE div, matches numpy
  t = fminf(fmaxf(t, -8.0f), 7.0f);
  t = rintf(t);  // RNE, matches np.round
  return (int)t;
}

// ---- means of alpha_a1 (768) and alpha_a2 (3072), f64 accumulate ----------
__global__ void means_k(const float* __restrict__ v1, int n1,
                        const float* __restrict__ v2, int n2,
                        float* __restrict__ out) {
  const float* src = blockIdx.x ? v2 : v1;
  const int n = blockIdx.x ? n2 : n1;
  __shared__ double red[256];
  double s = 0.0;
  for (int i = threadIdx.x; i < n; i += 256) s += (double)src[i];
  red[threadIdx.x] = s;
  __syncthreads();
  for (int st = 128; st > 0; st >>= 1) {
    if (threadIdx.x < st) red[threadIdx.x] += red[threadIdx.x + st];
    __syncthreads();
  }
  if (threadIdx.x == 0) {
    float m = (float)(red[0] / (double)n);
    out[blockIdx.x] = m;
    if (blockIdx.x == 1) {
      out[2] = 1.0f / m;
      out[3] = 0.5f * (1.0f / m);
    }
  }
}

// ---- quantize activations x0 -> xq i8 -------------------------------------
__global__ void quant_x_k(const float* __restrict__ x,
                          unsigned* __restrict__ xq,
                          const float* __restrict__ means, int n4) {
  int i = blockIdx.x * blockDim.x + threadIdx.x;
  if (i >= n4) return;
  const float a = means[0];
  float4 v = ((const float4*)x)[i];
  unsigned u = (q4_i8(v.x, a) & 0xFF) | ((q4_i8(v.y, a) & 0xFF) << 8) |
               ((q4_i8(v.z, a) & 0xFF) << 16) | ((q4_i8(v.w, a) & 0xFF) << 24);
  xq[i] = u;
}

// ---- quantize weights [R][C] natural order, per-row alpha -----------------
__global__ void quant_w_k(const float* __restrict__ w,
                          const float* __restrict__ alpha,
                          unsigned* __restrict__ wq, int C, int n4) {
  int i = blockIdx.x * blockDim.x + threadIdx.x;
  if (i >= n4) return;
  int row = (i * 4) / C;
  const float a = alpha[row];
  float4 v = ((const float4*)w)[i];
  unsigned u = (q4_i8(v.x, a) & 0xFF) | ((q4_i8(v.y, a) & 0xFF) << 8) |
               ((q4_i8(v.z, a) & 0xFF) << 16) | ((q4_i8(v.w, a) & 0xFF) << 24);
  wq[i] = u;
}

// ---- GEMM: C[M,N] = A[M,K] * B[N,K]^T, i8 MFMA 16x16x64 -------------------
// 512 threads / 8 waves, 128x128 tile, BK=64, double-buffered pipeline.
// Wave w: wm=w>>1 (0..3), wn=w&1; wave tile 32x64, acc[2][4].
// EPI==1: dequant+bias -> gelu(exact-erf approx) -> quant(a2) -> i8 hq
// EPI==2: dequant(a2,alpha_w2)+bias -> f32 out (bit-exact numpy chain)
template <int EPI>
__global__ __launch_bounds__(512, 6) void gemm_k(
    const signed char* __restrict__ A, const signed char* __restrict__ B,
    const float* __restrict__ alphaw, const float* __restrict__ bias,
    const float* __restrict__ means, signed char* __restrict__ out_b,
    float* __restrict__ out_f, int N, int K) {
  __shared__ __align__(16) signed char sA0[128 * 64];
  __shared__ __align__(16) signed char sB0[128 * 64];
  __shared__ __align__(16) signed char sA1[128 * 64];
  __shared__ __align__(16) signed char sB1[128 * 64];
  const int tid = threadIdx.x;
  const int w = tid >> 6;  // 0..7
  const int l = tid & 63;
  const int wm = w >> 1, wn = w & 1;
  const long bm0 = (long)blockIdx.y * 128;
  const long bn0 = (long)blockIdx.x * 128;

  i32x4 acc[2][4] = {};

  // staging: wave w covers rows w*16 + (l>>2); phys slot l&3 holds
  // logical slot (l&3)^(row&3) -> pre-swizzle the global source col.
  const int srow = l >> 2;                          // 0..15 within chunk
  const int scol = (((l & 3) ^ (srow & 3)) << 4);   // swizzled source col
  const int rsw = ((l >> 4) ^ (l & 3)) << 4;        // read-side phys slot*16

  const signed char* gA = A + (bm0 + w * 16 + srow) * (long)K + scol;
  const signed char* gB = B + (bn0 + w * 16 + srow) * (long)K + scol;

  auto STAGE = [&](signed char* dA, signed char* dB, int kt) {
    gload_lds16(gA + kt, dA + w * 1024);
    gload_lds16(gB + kt, dB + w * 1024);
  };
  auto COMPUTE = [&](const signed char* pA, const signed char* pB) {
    i32x4 af[2], bg[4];
#pragma unroll
    for (int m = 0; m < 2; ++m)
      af[m] = *(const i32x4*)&pA[(wm * 32 + m * 16 + (l & 15)) * 64 + rsw];
#pragma unroll
    for (int n = 0; n < 4; ++n)
      bg[n] = *(const i32x4*)&pB[(wn * 64 + n * 16 + (l & 15)) * 64 + rsw];
#pragma unroll
    for (int m = 0; m < 2; ++m)
#pragma unroll
      for (int n = 0; n < 4; ++n)
        acc[m][n] = __builtin_amdgcn_mfma_i32_16x16x64_i8(af[m], bg[n],
                                                          acc[m][n], 0, 0, 0);
  };

  // pipeline: stage(next) issued BEFORE compute(cur); __syncthreads drains
  // the in-flight stage AFTER a full compute phase (latency hidden).
  STAGE(sA0, sB0, 0);
  __syncthreads();
  for (int kt = 0; kt < K; kt += 128) {
    STAGE(sA1, sB1, kt + 64);
    COMPUTE(sA0, sB0);
    __syncthreads();
    if (kt + 128 < K) STAGE(sA0, sB0, kt + 128);
    COMPUTE(sA1, sB1);
    __syncthreads();
  }

  const float a1 = means[0];
  const float a2 = means[1];
  const float half_inv_a2 = means[3];

  float awc[4], bsc[4];
  const int cc0 = (int)bn0 + wn * 64 + (l & 15);
#pragma unroll
  for (int n = 0; n < 4; ++n) {
    awc[n] = alphaw[cc0 + n * 16];
    bsc[n] = bias[cc0 + n * 16];
  }

  const int r0 = (int)bm0 + wm * 32 + (l >> 4) * 4;

  if (EPI == 1) {
    float awa1[4];
#pragma unroll
    for (int n = 0; n < 4; ++n) awa1[n] = awc[n] * a1;
#pragma unroll
    for (int m = 0; m < 2; ++m) {
#pragma unroll
      for (int rg = 0; rg < 4; ++rg) {
        const int r = r0 + m * 16 + rg;
        signed char* prow = out_b + (size_t)r * N + cc0;
#pragma unroll
        for (int n = 0; n < 4; ++n) {
          const float f = (float)acc[m][n][rg];  // exact: |acc| < 2^18
          const float t = fmaf(f, awa1[n], bsc[n]);
          // exact-formula GELU via A&S 7.1.26 erf (|err|<=1.5e-7)
          const float x = t * 0.70710678118654752f;
          const float az = fabsf(x);
          const float rr = __builtin_amdgcn_rcpf(fmaf(0.3275911f, az, 1.0f));
          float p = fmaf(rr, 1.061405429f, -1.453152027f);
          p = fmaf(rr, p, 1.421413741f);
          p = fmaf(rr, p, -0.284496736f);
          p = fmaf(rr, p, 0.254829592f);
          p = p * rr;
          const float e = __expf(-az * az);
          float er = fmaf(-p, e, 1.0f);
          er = copysignf(er, x);
          // +/-10 clip dropped: 10/a2 > 7 always, saturation identical
          float qv = t * (1.0f + er) * half_inv_a2;
          qv = fminf(fmaxf(qv, -8.0f), 7.0f);
          qv = rintf(qv);
          prow[n * 16] = (signed char)(int)qv;
        }
      }
    }
  } else {
#pragma unroll
    for (int m = 0; m < 2; ++m) {
#pragma unroll
      for (int rg = 0; rg < 4; ++rg) {
        const int r = r0 + m * 16 + rg;
        float* prow = out_f + (size_t)r * N + cc0;
#pragma unroll
        for (int n = 0; n < 4; ++n) {
          const float f = (float)acc[m][n][rg];
          // bit-exact numpy chain: ((x*aw)*a2) + b, no FMA contraction
          float t = __fmul_rn(f, awc[n]);
          t = __fmul_rn(t, a2);
          t = __fadd_rn(t, bsc[n]);
          prow[n * 16] = t;
        }
      }
    }
  }
}

extern "C" void kernel_launch(void* const* d_in, const int* in_sizes, int n_in,
                              void* d_out, int out_size, void* d_ws,
                              size_t ws_size, hipStream_t stream) {
  const float* x0 = (const float*)d_in[0];
  const float* w1 = (const float*)d_in[1];
  const float* b1 = (const float*)d_in[2];
  const float* aw1 = (const float*)d_in[3];
  const float* aa1 = (const float*)d_in[4];
  const float* w2 = (const float*)d_in[5];
  const float* b2 = (const float*)d_in[6];
  const float* aw2 = (const float*)d_in[7];
  const float* aa2 = (const float*)d_in[8];

  char* ws = (char*)d_ws;
  float* means = (float*)ws;
  signed char* xq = (signed char*)(ws + 256);
  signed char* wq1 = (signed char*)(ws + 12583168);
  signed char* wq2 = (signed char*)(ws + 14942464);
  signed char* hq = (signed char*)(ws + 17301760);

  // 1) means of alpha_a1 / alpha_a2 (+ 1/a2, 0.5/a2)
  means_k<<<2, 256, 0, stream>>>(aa1, 768, aa2, 3072, means);
  // 2) quantize activations and weights to i8 (natural layouts)
  quant_x_k<<<12288, 256, 0, stream>>>(x0, (unsigned*)xq, means, 3145728);
  quant_w_k<<<2304, 256, 0, stream>>>(w1, aw1, (unsigned*)wq1, 768, 589824);
  quant_w_k<<<2304, 256, 0, stream>>>(w2, aw2, (unsigned*)wq2, 3072, 589824);
  // 3) GEMM1 [16384,768]x[3072,768]^T + gelu + requant -> hq (i8)
  dim3 g1(24, 128);
  gemm_k<1><<<g1, 512, 0, stream>>>(xq, wq1, aw1, b1, means, hq, nullptr, 3072,
                                    768);
  // 4) GEMM2 [16384,3072]x[768,3072]^T + bias -> f32 out
  dim3 g2(6, 128);
  gemm_k<2><<<g2, 512, 0, stream>>>(hq, wq2, aw2, b2, means, nullptr,
                                    (float*)d_out, 768, 3072);
}

// Round 9
// 144.089 us; speedup vs baseline: 1.1644x; 1.0521x over previous
//
#include <hip/hip_runtime.h>
#include <hip/hip_bf16.h>
#include <math.h>

// ---------------------------------------------------------------------------
// Q_Mlp: x0 -> int4-quant -> GEMM1(K=768) -> dequant+GELU+clip -> int4-quant
//        -> GEMM2(K=3072) -> dequant+bias -> out (f32)
// Quantized operands are integers in [-8,7]: exact in int8. i8 MFMA
// (16x16x64, 2x bf16 rate) with i32 accumulation (max |acc| < 2^18, exact).
//
// Ledger: r6 = gemm1(256t,BK128,LB4) 78.6us + gemm2(512t,BK128,LB6) 43us +
// pre 15us = 136.5. r8 taught: BK=64 swizzle was 4-way-conflicted (7.1M =
// 4 cyc/read exactly; 64B pitch rows span only 16 banks and slot parity
// tracked row parity) and BK=64 halves MFMA/barrier -> both gemms regressed.
//
// This round: BOTH gemms use the proven 512t / BK=128 / single-buffer /
// zero-conflict-swizzle structure (r6's gemm2). gemm1 gains wave-TLP:
// 512t @ VGPR<=64 (measured 48) -> __launch_bounds__(512,8) -> 4 blocks/CU
// x 8 waves = 32 waves/CU (vs 16 at 256t/LB4). gemm2 kept EXACTLY at r6's
// proven (512,6) config.
//
// LDS bank-conflict fix (T2, rule #21 both-sides involution), verified 0 @BK128:
//   col ^= ((row&7)<<4); staging pre-swizzles the GLOBAL source col
//   (global_load_lds dest stays linear); fragment read applies the same XOR.
//   At 128B pitch bank = f(slot) only -> uniform spread, 0 conflicts.
//
// Workspace layout (bytes):
//   [0,256)              : a1, a2, inv_a2, 0.5*inv_a2 (f32)
//   [256, +12582912)     : xq  i8 [16384][768]
//   [12583168, +2359296) : wq1 i8 [3072][768]
//   [14942464, +2359296) : wq2 i8 [768][3072]
//   [17301760, +50331648): hq  i8 [16384][3072]
// ---------------------------------------------------------------------------

typedef __attribute__((ext_vector_type(4))) int i32x4;

__device__ __forceinline__ void gload_lds16(const void* g, void* l) {
  __builtin_amdgcn_global_load_lds(
      (const __attribute__((address_space(1))) void*)g,
      (__attribute__((address_space(3))) void*)l, 16, 0, 0);
}

// quantize: round-half-even(clip(x/a, -8, 7)) -> int in [-8,7]
__device__ __forceinline__ int q4_i8(float x, float a) {
  float t = x / a;  // IEEE div, matches numpy
  t = fminf(fmaxf(t, -8.0f), 7.0f);
  t = rintf(t);  // RNE, matches np.round
  return (int)t;
}

// ---- means of alpha_a1 (768) and alpha_a2 (3072), f64 accumulate ----------
__global__ void means_k(const float* __restrict__ v1, int n1,
                        const float* __restrict__ v2, int n2,
                        float* __restrict__ out) {
  const float* src = blockIdx.x ? v2 : v1;
  const int n = blockIdx.x ? n2 : n1;
  __shared__ double red[256];
  double s = 0.0;
  for (int i = threadIdx.x; i < n; i += 256) s += (double)src[i];
  red[threadIdx.x] = s;
  __syncthreads();
  for (int st = 128; st > 0; st >>= 1) {
    if (threadIdx.x < st) red[threadIdx.x] += red[threadIdx.x + st];
    __syncthreads();
  }
  if (threadIdx.x == 0) {
    float m = (float)(red[0] / (double)n);
    out[blockIdx.x] = m;
    if (blockIdx.x == 1) {
      out[2] = 1.0f / m;
      out[3] = 0.5f * (1.0f / m);
    }
  }
}

// ---- quantize activations x0 -> xq i8 -------------------------------------
__global__ void quant_x_k(const float* __restrict__ x,
                          unsigned* __restrict__ xq,
                          const float* __restrict__ means, int n4) {
  int i = blockIdx.x * blockDim.x + threadIdx.x;
  if (i >= n4) return;
  const float a = means[0];
  float4 v = ((const float4*)x)[i];
  unsigned u = (q4_i8(v.x, a) & 0xFF) | ((q4_i8(v.y, a) & 0xFF) << 8) |
               ((q4_i8(v.z, a) & 0xFF) << 16) | ((q4_i8(v.w, a) & 0xFF) << 24);
  xq[i] = u;
}

// ---- quantize weights [R][C] natural order, per-row alpha -----------------
__global__ void quant_w_k(const float* __restrict__ w,
                          const float* __restrict__ alpha,
                          unsigned* __restrict__ wq, int C, int n4) {
  int i = blockIdx.x * blockDim.x + threadIdx.x;
  if (i >= n4) return;
  int row = (i * 4) / C;
  const float a = alpha[row];
  float4 v = ((const float4*)w)[i];
  unsigned u = (q4_i8(v.x, a) & 0xFF) | ((q4_i8(v.y, a) & 0xFF) << 8) |
               ((q4_i8(v.z, a) & 0xFF) << 16) | ((q4_i8(v.w, a) & 0xFF) << 24);
  wq[i] = u;
}

// ---- GEMM1: C = A[M,K]*B[N,K]^T, 512t/8 waves, 128x128, BK=128, LB(512,8) -
// dequant+bias -> gelu(exact-erf approx) -> quant(a2) -> i8 hq
__global__ __launch_bounds__(512, 8) void gemm1_k(
    const signed char* __restrict__ A, const signed char* __restrict__ B,
    const float* __restrict__ alphaw, const float* __restrict__ bias,
    const float* __restrict__ means, signed char* __restrict__ out_b, int N,
    int K) {
  __shared__ __align__(16) signed char sA[128 * 128];
  __shared__ __align__(16) signed char sB[128 * 128];
  const int tid = threadIdx.x;
  const int w = tid >> 6;  // 0..7
  const int l = tid & 63;
  const int wm = w >> 1, wn = w & 1;
  const long bm0 = (long)blockIdx.y * 128;
  const long bn0 = (long)blockIdx.x * 128;

  i32x4 acc[2][4] = {};

  const int srow = l >> 3;                        // row-within-chunk 0..7
  const int scol = ((l & 7) * 16) ^ (srow << 4);  // pre-swizzled src col
  const int rsw = (l & 7) << 4;                   // read-side XOR

  const signed char* gA = A + (bm0 + w * 16 + srow) * (long)K + scol;
  const signed char* gB = B + (bn0 + w * 16 + srow) * (long)K + scol;

  for (int kt = 0; kt < K; kt += 128) {
    __syncthreads();  // previous tile's LDS reads done
#pragma unroll
    for (int i = 0; i < 2; ++i) {  // wave stages chunks 2w+i (A and B)
      gload_lds16(gA + (long)i * 8 * K + kt, &sA[(w * 2 + i) * 1024]);
      gload_lds16(gB + (long)i * 8 * K + kt, &sB[(w * 2 + i) * 1024]);
    }
    __syncthreads();  // staging visible (compiler drains vmcnt)
#pragma unroll
    for (int kk = 0; kk < 2; ++kk) {
      const int kc = (kk * 64 + (l >> 4) * 16) ^ rsw;  // swizzled k-col
      i32x4 af[2], bg[4];
#pragma unroll
      for (int m = 0; m < 2; ++m)
        af[m] = *(const i32x4*)&sA[(wm * 32 + m * 16 + (l & 15)) * 128 + kc];
#pragma unroll
      for (int n = 0; n < 4; ++n)
        bg[n] = *(const i32x4*)&sB[(wn * 64 + n * 16 + (l & 15)) * 128 + kc];
#pragma unroll
      for (int m = 0; m < 2; ++m)
#pragma unroll
        for (int n = 0; n < 4; ++n)
          acc[m][n] = __builtin_amdgcn_mfma_i32_16x16x64_i8(af[m], bg[n],
                                                            acc[m][n], 0, 0, 0);
    }
  }

  const float a1 = means[0];
  const float half_inv_a2 = means[3];

  float awa1[4], bsc[4];
  const int cc0 = (int)bn0 + wn * 64 + (l & 15);
#pragma unroll
  for (int n = 0; n < 4; ++n) {
    awa1[n] = alphaw[cc0 + n * 16] * a1;
    bsc[n] = bias[cc0 + n * 16];
  }

  const int r0 = (int)bm0 + wm * 32 + (l >> 4) * 4;

#pragma unroll
  for (int m = 0; m < 2; ++m) {
#pragma unroll
    for (int rg = 0; rg < 4; ++rg) {
      const int r = r0 + m * 16 + rg;
      signed char* prow = out_b + (size_t)r * N + cc0;
#pragma unroll
      for (int n = 0; n < 4; ++n) {
        const float f = (float)acc[m][n][rg];  // exact: |acc| < 2^18
        const float t = fmaf(f, awa1[n], bsc[n]);
        // exact-formula GELU via A&S 7.1.26 erf (|err|<=1.5e-7)
        const float x = t * 0.70710678118654752f;
        const float az = fabsf(x);
        const float rr = __builtin_amdgcn_rcpf(fmaf(0.3275911f, az, 1.0f));
        float p = fmaf(rr, 1.061405429f, -1.453152027f);
        p = fmaf(rr, p, 1.421413741f);
        p = fmaf(rr, p, -0.284496736f);
        p = fmaf(rr, p, 0.254829592f);
        p = p * rr;
        const float e = __expf(-az * az);
        float er = fmaf(-p, e, 1.0f);
        er = copysignf(er, x);
        // +/-10 clip dropped: 10/a2 > 7 always, saturation identical
        float qv = t * (1.0f + er) * half_inv_a2;
        qv = fminf(fmaxf(qv, -8.0f), 7.0f);
        qv = rintf(qv);
        prow[n * 16] = (signed char)(int)qv;
      }
    }
  }
}

// ---- GEMM2: C = A[M,K]*B[N,K]^T, 512t/8 waves, 128x128, BK=128 ------------
// EXACT r6 proven config (43us). dequant(a2,alpha_w2)+bias -> f32 out.
__global__ __launch_bounds__(512, 6) void gemm2_k(
    const signed char* __restrict__ A, const signed char* __restrict__ B,
    const float* __restrict__ alphaw, const float* __restrict__ bias,
    const float* __restrict__ means, float* __restrict__ out_f, int N, int K) {
  __shared__ __align__(16) signed char sA[128 * 128];
  __shared__ __align__(16) signed char sB[128 * 128];
  const int tid = threadIdx.x;
  const int w = tid >> 6;  // 0..7
  const int l = tid & 63;
  const int wm = w >> 1, wn = w & 1;
  const long bm0 = (long)blockIdx.y * 128;
  const long bn0 = (long)blockIdx.x * 128;

  i32x4 acc[2][4] = {};

  const int srow = l >> 3;                        // row-within-chunk 0..7
  const int scol = ((l & 7) * 16) ^ (srow << 4);  // pre-swizzled src col
  const int rsw = (l & 7) << 4;                   // read-side XOR

  const signed char* gA = A + (bm0 + w * 16 + srow) * (long)K + scol;
  const signed char* gB = B + (bn0 + w * 16 + srow) * (long)K + scol;

  for (int kt = 0; kt < K; kt += 128) {
    __syncthreads();  // previous tile's LDS reads done
#pragma unroll
    for (int i = 0; i < 2; ++i) {  // wave stages chunks 2w+i (A and B)
      gload_lds16(gA + (long)i * 8 * K + kt, &sA[(w * 2 + i) * 1024]);
      gload_lds16(gB + (long)i * 8 * K + kt, &sB[(w * 2 + i) * 1024]);
    }
    __syncthreads();  // staging visible (compiler drains vmcnt)
#pragma unroll
    for (int kk = 0; kk < 2; ++kk) {
      const int kc = (kk * 64 + (l >> 4) * 16) ^ rsw;  // swizzled k-col
      i32x4 af[2], bg[4];
#pragma unroll
      for (int m = 0; m < 2; ++m)
        af[m] = *(const i32x4*)&sA[(wm * 32 + m * 16 + (l & 15)) * 128 + kc];
#pragma unroll
      for (int n = 0; n < 4; ++n)
        bg[n] = *(const i32x4*)&sB[(wn * 64 + n * 16 + (l & 15)) * 128 + kc];
#pragma unroll
      for (int m = 0; m < 2; ++m)
#pragma unroll
        for (int n = 0; n < 4; ++n)
          acc[m][n] = __builtin_amdgcn_mfma_i32_16x16x64_i8(af[m], bg[n],
                                                            acc[m][n], 0, 0, 0);
    }
  }

  const float a2 = means[1];

  float awc[4], bsc[4];
  const int cc0 = (int)bn0 + wn * 64 + (l & 15);
#pragma unroll
  for (int n = 0; n < 4; ++n) {
    awc[n] = alphaw[cc0 + n * 16];
    bsc[n] = bias[cc0 + n * 16];
  }

  const int r0 = (int)bm0 + wm * 32 + (l >> 4) * 4;

#pragma unroll
  for (int m = 0; m < 2; ++m) {
#pragma unroll
    for (int rg = 0; rg < 4; ++rg) {
      const int r = r0 + m * 16 + rg;
      float* prow = out_f + (size_t)r * N + cc0;
#pragma unroll
      for (int n = 0; n < 4; ++n) {
        const float f = (float)acc[m][n][rg];
        // bit-exact numpy chain: ((x*aw)*a2) + b, no FMA contraction
        float t = __fmul_rn(f, awc[n]);
        t = __fmul_rn(t, a2);
        t = __fadd_rn(t, bsc[n]);
        prow[n * 16] = t;
      }
    }
  }
}

extern "C" void kernel_launch(void* const* d_in, const int* in_sizes, int n_in,
                              void* d_out, int out_size, void* d_ws,
                              size_t ws_size, hipStream_t stream) {
  const float* x0 = (const float*)d_in[0];
  const float* w1 = (const float*)d_in[1];
  const float* b1 = (const float*)d_in[2];
  const float* aw1 = (const float*)d_in[3];
  const float* aa1 = (const float*)d_in[4];
  const float* w2 = (const float*)d_in[5];
  const float* b2 = (const float*)d_in[6];
  const float* aw2 = (const float*)d_in[7];
  const float* aa2 = (const float*)d_in[8];

  char* ws = (char*)d_ws;
  float* means = (float*)ws;
  signed char* xq = (signed char*)(ws + 256);
  signed char* wq1 = (signed char*)(ws + 12583168);
  signed char* wq2 = (signed char*)(ws + 14942464);
  signed char* hq = (signed char*)(ws + 17301760);

  // 1) means of alpha_a1 / alpha_a2 (+ 1/a2, 0.5/a2)
  means_k<<<2, 256, 0, stream>>>(aa1, 768, aa2, 3072, means);
  // 2) quantize activations and weights to i8 (natural layouts)
  quant_x_k<<<12288, 256, 0, stream>>>(x0, (unsigned*)xq, means, 3145728);
  quant_w_k<<<2304, 256, 0, stream>>>(w1, aw1, (unsigned*)wq1, 768, 589824);
  quant_w_k<<<2304, 256, 0, stream>>>(w2, aw2, (unsigned*)wq2, 3072, 589824);
  // 3) GEMM1 [16384,768]x[3072,768]^T + gelu + requant -> hq (i8)
  dim3 g1(24, 128);
  gemm1_k<<<g1, 512, 0, stream>>>(xq, wq1, aw1, b1, means, hq, 3072, 768);
  // 4) GEMM2 [16384,3072]x[768,3072]^T + bias -> f32 out
  dim3 g2(6, 128);
  gemm2_k<<<g2, 512, 0, stream>>>(hq, wq2, aw2, b2, means, (float*)d_out, 768,
                                  3072);
}

// Round 10
// 143.798 us; speedup vs baseline: 1.1668x; 1.0020x over previous
//
#include <hip/hip_runtime.h>
#include <hip/hip_bf16.h>
#include <math.h>

// ---------------------------------------------------------------------------
// Q_Mlp: x0 -> int4-quant -> GEMM1(K=768) -> dequant+GELU+clip -> int4-quant
//        -> GEMM2(K=3072) -> dequant+bias -> out (f32)
// Quantized operands are integers in [-8,7]: exact in int8. i8 MFMA
// (16x16x64, 2x bf16 rate) with i32 accumulation (max |acc| < 2^18, exact).
//
// Ledger: gemm1@512t/LB8 74.7us (r9), gemm2@512t/LB6 43us (r6), pre ~18us.
// r9 signal: gemm1 WRITE_SIZE 49->61MB (byte-store partial-line RMW at 4
// blocks/CU) + VALUBusy 59% (epilogue). This round: k-permutation packed
// dword stores (verified bit-exact in r7; masked there by LB5 spill).
//
// K-permutation: GEMM invariant under k-perm applied to BOTH operands.
// hq phys byte (within each 64-col group) = c*4 + n for logical col n*16+c.
// gemm1 packs its 4 per-row bytes into ONE dword store (8 dword-stores vs
// 32 byte-stores; lanes 0..15 -> dense 64B segments). quant_w2 applies the
// same perm to wq2's k-dim; gemm2 reads both in phys order -> identical dots.
//
// LDS swizzle (T2, both-sides involution, verified 0 conflicts @BK128):
//   col ^= ((row&7)<<4); stage pre-swizzles the GLOBAL source col
//   (global_load_lds dest stays linear); fragment read applies the same XOR.
//
// Workspace layout (bytes):
//   [0,256)              : a1, a2, inv_a2, 0.5*inv_a2 (f32)
//   [256, +12582912)     : xq  i8 [16384][768]
//   [12583168, +2359296) : wq1 i8 [3072][768]
//   [14942464, +2359296) : wq2 i8 [768][3072]  (k-permuted)
//   [17301760, +50331648): hq  i8 [16384][3072] (k-permuted)
// ---------------------------------------------------------------------------

typedef __attribute__((ext_vector_type(4))) int i32x4;

__device__ __forceinline__ void gload_lds16(const void* g, void* l) {
  __builtin_amdgcn_global_load_lds(
      (const __attribute__((address_space(1))) void*)g,
      (__attribute__((address_space(3))) void*)l, 16, 0, 0);
}

// quantize: round-half-even(clip(x/a, -8, 7)) -> int in [-8,7]
__device__ __forceinline__ int q4_i8(float x, float a) {
  float t = x / a;  // IEEE div, matches numpy
  t = fminf(fmaxf(t, -8.0f), 7.0f);
  t = rintf(t);  // RNE, matches np.round
  return (int)t;
}

// ---- means of alpha_a1 (768) and alpha_a2 (3072), f64 accumulate ----------
__global__ void means_k(const float* __restrict__ v1, int n1,
                        const float* __restrict__ v2, int n2,
                        float* __restrict__ out) {
  const float* src = blockIdx.x ? v2 : v1;
  const int n = blockIdx.x ? n2 : n1;
  __shared__ double red[256];
  double s = 0.0;
  for (int i = threadIdx.x; i < n; i += 256) s += (double)src[i];
  red[threadIdx.x] = s;
  __syncthreads();
  for (int st = 128; st > 0; st >>= 1) {
    if (threadIdx.x < st) red[threadIdx.x] += red[threadIdx.x + st];
    __syncthreads();
  }
  if (threadIdx.x == 0) {
    float m = (float)(red[0] / (double)n);
    out[blockIdx.x] = m;
    if (blockIdx.x == 1) {
      out[2] = 1.0f / m;
      out[3] = 0.5f * (1.0f / m);
    }
  }
}

// ---- quantize activations x0 -> xq i8 -------------------------------------
__global__ void quant_x_k(const float* __restrict__ x,
                          unsigned* __restrict__ xq,
                          const float* __restrict__ means, int n4) {
  int i = blockIdx.x * blockDim.x + threadIdx.x;
  if (i >= n4) return;
  const float a = means[0];
  float4 v = ((const float4*)x)[i];
  unsigned u = (q4_i8(v.x, a) & 0xFF) | ((q4_i8(v.y, a) & 0xFF) << 8) |
               ((q4_i8(v.z, a) & 0xFF) << 16) | ((q4_i8(v.w, a) & 0xFF) << 24);
  xq[i] = u;
}

// ---- quantize weights w1 [R][C] natural order, per-row alpha --------------
__global__ void quant_w_k(const float* __restrict__ w,
                          const float* __restrict__ alpha,
                          unsigned* __restrict__ wq, int C, int n4) {
  int i = blockIdx.x * blockDim.x + threadIdx.x;
  if (i >= n4) return;
  int row = (i * 4) / C;
  const float a = alpha[row];
  float4 v = ((const float4*)w)[i];
  unsigned u = (q4_i8(v.x, a) & 0xFF) | ((q4_i8(v.y, a) & 0xFF) << 8) |
               ((q4_i8(v.z, a) & 0xFF) << 16) | ((q4_i8(v.w, a) & 0xFF) << 24);
  wq[i] = u;
}

// ---- quantize w2 [768][3072] with k-PERMUTED layout -----------------------
// phys dword p in row: g = p>>4, c = p&15; packs logical cols g*64 + n*16 + c
// for n = 0..3 (byte n). Matches gemm1's hq write permutation (r7-verified).
__global__ void quant_w2_k(const float* __restrict__ w,
                           const float* __restrict__ alpha,
                           unsigned* __restrict__ wq, int nd) {
  int i = blockIdx.x * blockDim.x + threadIdx.x;
  if (i >= nd) return;  // nd = 768*768 dwords
  const int row = i / 768;
  const int p = i - row * 768;
  const int g = p >> 4, c = p & 15;
  const float a = alpha[row];
  const float* src = w + (size_t)row * 3072 + g * 64 + c;
  unsigned d = 0;
#pragma unroll
  for (int n = 0; n < 4; ++n)
    d |= ((unsigned)(q4_i8(src[n * 16], a) & 0xFF)) << (8 * n);
  wq[i] = d;
}

// ---- GEMM1: C = A[M,K]*B[N,K]^T, 512t/8 waves, 128x128, BK=128, LB(512,8) -
// dequant+bias -> gelu(exact-erf approx) -> quant(a2) -> packed-dword i8 hq
__global__ __launch_bounds__(512, 8) void gemm1_k(
    const signed char* __restrict__ A, const signed char* __restrict__ B,
    const float* __restrict__ alphaw, const float* __restrict__ bias,
    const float* __restrict__ means, unsigned* __restrict__ out_u, int N,
    int K) {
  __shared__ __align__(16) signed char sA[128 * 128];
  __shared__ __align__(16) signed char sB[128 * 128];
  const int tid = threadIdx.x;
  const int w = tid >> 6;  // 0..7
  const int l = tid & 63;
  const int wm = w >> 1, wn = w & 1;
  const long bm0 = (long)blockIdx.y * 128;
  const long bn0 = (long)blockIdx.x * 128;

  i32x4 acc[2][4] = {};

  const int srow = l >> 3;                        // row-within-chunk 0..7
  const int scol = ((l & 7) * 16) ^ (srow << 4);  // pre-swizzled src col
  const int rsw = (l & 7) << 4;                   // read-side XOR

  const signed char* gA = A + (bm0 + w * 16 + srow) * (long)K + scol;
  const signed char* gB = B + (bn0 + w * 16 + srow) * (long)K + scol;

  for (int kt = 0; kt < K; kt += 128) {
    __syncthreads();  // previous tile's LDS reads done
#pragma unroll
    for (int i = 0; i < 2; ++i) {  // wave stages chunks 2w+i (A and B)
      gload_lds16(gA + (long)i * 8 * K + kt, &sA[(w * 2 + i) * 1024]);
      gload_lds16(gB + (long)i * 8 * K + kt, &sB[(w * 2 + i) * 1024]);
    }
    __syncthreads();  // staging visible (compiler drains vmcnt)
#pragma unroll
    for (int kk = 0; kk < 2; ++kk) {
      const int kc = (kk * 64 + (l >> 4) * 16) ^ rsw;  // swizzled k-col
      i32x4 af[2], bg[4];
#pragma unroll
      for (int m = 0; m < 2; ++m)
        af[m] = *(const i32x4*)&sA[(wm * 32 + m * 16 + (l & 15)) * 128 + kc];
#pragma unroll
      for (int n = 0; n < 4; ++n)
        bg[n] = *(const i32x4*)&sB[(wn * 64 + n * 16 + (l & 15)) * 128 + kc];
#pragma unroll
      for (int m = 0; m < 2; ++m)
#pragma unroll
        for (int n = 0; n < 4; ++n)
          acc[m][n] = __builtin_amdgcn_mfma_i32_16x16x64_i8(af[m], bg[n],
                                                            acc[m][n], 0, 0, 0);
    }
  }

  const float a1 = means[0];
  const float half_inv_a2 = means[3];

  float awa1[4], bsc[4];
  const int cc0 = (int)bn0 + wn * 64 + (l & 15);  // logical col base
#pragma unroll
  for (int n = 0; n < 4; ++n) {
    awa1[n] = alphaw[cc0 + n * 16] * a1;
    bsc[n] = bias[cc0 + n * 16];
  }

  const int r0 = (int)bm0 + wm * 32 + (l >> 4) * 4;
  const int Nd = N >> 2;                                // dwords per row
  const int pd = ((int)bn0 >> 2) + wn * 16 + (l & 15);  // phys dword in row

#pragma unroll
  for (int m = 0; m < 2; ++m) {
#pragma unroll
    for (int rg = 0; rg < 4; ++rg) {
      const int r = r0 + m * 16 + rg;
      unsigned d = 0;
#pragma unroll
      for (int n = 0; n < 4; ++n) {
        const float f = (float)acc[m][n][rg];  // exact: |acc| < 2^18
        const float t = fmaf(f, awa1[n], bsc[n]);
        // exact-formula GELU via A&S 7.1.26 erf (|err|<=1.5e-7)
        const float x = t * 0.70710678118654752f;
        const float az = fabsf(x);
        const float rr = __builtin_amdgcn_rcpf(fmaf(0.3275911f, az, 1.0f));
        float p = fmaf(rr, 1.061405429f, -1.453152027f);
        p = fmaf(rr, p, 1.421413741f);
        p = fmaf(rr, p, -0.284496736f);
        p = fmaf(rr, p, 0.254829592f);
        p = p * rr;
        const float e = __expf(-az * az);
        float er = fmaf(-p, e, 1.0f);
        er = copysignf(er, x);
        // +/-10 clip dropped: 10/a2 > 7 always, saturation identical
        float qv = t * (1.0f + er) * half_inv_a2;
        qv = fminf(fmaxf(qv, -8.0f), 7.0f);
        qv = rintf(qv);
        d |= ((unsigned)((int)qv & 0xFF)) << (8 * n);  // phys byte c*4+n
      }
      out_u[(size_t)r * Nd + pd] = d;
    }
  }
}

// ---- GEMM2: C = A[M,K]*B[N,K]^T, 512t/8 waves, 128x128, BK=128 ------------
// A = hq, B = wq2, both k-permuted identically -> dots unchanged.
// EXACT r6 proven config. dequant(a2,alpha_w2)+bias -> f32 out.
__global__ __launch_bounds__(512, 6) void gemm2_k(
    const signed char* __restrict__ A, const signed char* __restrict__ B,
    const float* __restrict__ alphaw, const float* __restrict__ bias,
    const float* __restrict__ means, float* __restrict__ out_f, int N, int K) {
  __shared__ __align__(16) signed char sA[128 * 128];
  __shared__ __align__(16) signed char sB[128 * 128];
  const int tid = threadIdx.x;
  const int w = tid >> 6;  // 0..7
  const int l = tid & 63;
  const int wm = w >> 1, wn = w & 1;
  const long bm0 = (long)blockIdx.y * 128;
  const long bn0 = (long)blockIdx.x * 128;

  i32x4 acc[2][4] = {};

  const int srow = l >> 3;                        // row-within-chunk 0..7
  const int scol = ((l & 7) * 16) ^ (srow << 4);  // pre-swizzled src col
  const int rsw = (l & 7) << 4;                   // read-side XOR

  const signed char* gA = A + (bm0 + w * 16 + srow) * (long)K + scol;
  const signed char* gB = B + (bn0 + w * 16 + srow) * (long)K + scol;

  for (int kt = 0; kt < K; kt += 128) {
    __syncthreads();  // previous tile's LDS reads done
#pragma unroll
    for (int i = 0; i < 2; ++i) {  // wave stages chunks 2w+i (A and B)
      gload_lds16(gA + (long)i * 8 * K + kt, &sA[(w * 2 + i) * 1024]);
      gload_lds16(gB + (long)i * 8 * K + kt, &sB[(w * 2 + i) * 1024]);
    }
    __syncthreads();  // staging visible (compiler drains vmcnt)
#pragma unroll
    for (int kk = 0; kk < 2; ++kk) {
      const int kc = (kk * 64 + (l >> 4) * 16) ^ rsw;  // swizzled k-col
      i32x4 af[2], bg[4];
#pragma unroll
      for (int m = 0; m < 2; ++m)
        af[m] = *(const i32x4*)&sA[(wm * 32 + m * 16 + (l & 15)) * 128 + kc];
#pragma unroll
      for (int n = 0; n < 4; ++n)
        bg[n] = *(const i32x4*)&sB[(wn * 64 + n * 16 + (l & 15)) * 128 + kc];
#pragma unroll
      for (int m = 0; m < 2; ++m)
#pragma unroll
        for (int n = 0; n < 4; ++n)
          acc[m][n] = __builtin_amdgcn_mfma_i32_16x16x64_i8(af[m], bg[n],
                                                            acc[m][n], 0, 0, 0);
    }
  }

  const float a2 = means[1];

  float awc[4], bsc[4];
  const int cc0 = (int)bn0 + wn * 64 + (l & 15);
#pragma unroll
  for (int n = 0; n < 4; ++n) {
    awc[n] = alphaw[cc0 + n * 16];
    bsc[n] = bias[cc0 + n * 16];
  }

  const int r0 = (int)bm0 + wm * 32 + (l >> 4) * 4;

#pragma unroll
  for (int m = 0; m < 2; ++m) {
#pragma unroll
    for (int rg = 0; rg < 4; ++rg) {
      const int r = r0 + m * 16 + rg;
      float* prow = out_f + (size_t)r * N + cc0;
#pragma unroll
      for (int n = 0; n < 4; ++n) {
        const float f = (float)acc[m][n][rg];
        // bit-exact numpy chain: ((x*aw)*a2) + b, no FMA contraction
        float t = __fmul_rn(f, awc[n]);
        t = __fmul_rn(t, a2);
        t = __fadd_rn(t, bsc[n]);
        prow[n * 16] = t;
      }
    }
  }
}

extern "C" void kernel_launch(void* const* d_in, const int* in_sizes, int n_in,
                              void* d_out, int out_size, void* d_ws,
                              size_t ws_size, hipStream_t stream) {
  const float* x0 = (const float*)d_in[0];
  const float* w1 = (const float*)d_in[1];
  const float* b1 = (const float*)d_in[2];
  const float* aw1 = (const float*)d_in[3];
  const float* aa1 = (const float*)d_in[4];
  const float* w2 = (const float*)d_in[5];
  const float* b2 = (const float*)d_in[6];
  const float* aw2 = (const float*)d_in[7];
  const float* aa2 = (const float*)d_in[8];

  char* ws = (char*)d_ws;
  float* means = (float*)ws;
  signed char* xq = (signed char*)(ws + 256);
  signed char* wq1 = (signed char*)(ws + 12583168);
  signed char* wq2 = (signed char*)(ws + 14942464);
  signed char* hq = (signed char*)(ws + 17301760);

  // 1) means of alpha_a1 / alpha_a2 (+ 1/a2, 0.5/a2)
  means_k<<<2, 256, 0, stream>>>(aa1, 768, aa2, 3072, means);
  // 2) quantize activations and weights to i8 (wq2 k-permuted)
  quant_x_k<<<12288, 256, 0, stream>>>(x0, (unsigned*)xq, means, 3145728);
  quant_w_k<<<2304, 256, 0, stream>>>(w1, aw1, (unsigned*)wq1, 768, 589824);
  quant_w2_k<<<2304, 256, 0, stream>>>(w2, aw2, (unsigned*)wq2, 589824);
  // 3) GEMM1 [16384,768]x[3072,768]^T + gelu + requant -> hq (packed dwords)
  dim3 g1(24, 128);
  gemm1_k<<<g1, 512, 0, stream>>>(xq, wq1, aw1, b1, means, (unsigned*)hq, 3072,
                                  768);
  // 4) GEMM2 [16384,3072]x[768,3072]^T + bias -> f32 out
  dim3 g2(6, 128);
  gemm2_k<<<g2, 512, 0, stream>>>(hq, wq2, aw2, b2, means, (float*)d_out, 768,
                                  3072);
}

// Round 11
// 141.110 us; speedup vs baseline: 1.1890x; 1.0190x over previous
//
#include <hip/hip_runtime.h>
#include <hip/hip_bf16.h>
#include <math.h>

// ---------------------------------------------------------------------------
// Q_Mlp: x0 -> int4-quant -> GEMM1(K=768) -> dequant+GELU+clip -> int4-quant
//        -> GEMM2(K=3072) -> dequant+bias -> out (f32)
// Quantized operands are integers in [-8,7]: exact in int8. i8 MFMA
// (16x16x64, 2x bf16 rate) with i32 accumulation (max |acc| < 2^18, exact).
//
// Ledger: gemm1@512t 74.5us (r9/r10), gemm2@512t/LB6 43us (r6), pre ~18us.
// r10 lesson: packed stores = no change; gemm1 is SCHEDULE-bound (MfmaUtil 22,
// VALU 61, both half-idle). r4/r8 dbufs failed because __syncthreads drains
// vmcnt(0) (m218: dbuf-with-drain0 == no dbuf). This round: T3+T4 counted
// vmcnt on gemm1 -- STAGE(next)->vmcnt(4)->s_barrier->COMPUTE->s_barrier.
// The second barrier is raw (no drain): it only orders compute(buf) before
// the next overwrite of buf. vmcnt(4) leaves the next tile's 4 loads in
// flight across the barrier. K templated so waits are literals.
//
// LDS swizzle (T2, both-sides involution, verified 0 conflicts @BK128):
//   col ^= ((row&7)<<4); stage pre-swizzles the GLOBAL source col
//   (global_load_lds dest stays linear); fragment read applies the same XOR.
//
// Workspace layout (bytes):
//   [0,256)              : a1, a2, inv_a2, 0.5*inv_a2 (f32)
//   [256, +12582912)     : xq  i8 [16384][768]
//   [12583168, +2359296) : wq1 i8 [3072][768]
//   [14942464, +2359296) : wq2 i8 [768][3072]
//   [17301760, +50331648): hq  i8 [16384][3072]
// ---------------------------------------------------------------------------

typedef __attribute__((ext_vector_type(4))) int i32x4;

__device__ __forceinline__ void gload_lds16(const void* g, void* l) {
  __builtin_amdgcn_global_load_lds(
      (const __attribute__((address_space(1))) void*)g,
      (__attribute__((address_space(3))) void*)l, 16, 0, 0);
}

// quantize: round-half-even(clip(x/a, -8, 7)) -> int in [-8,7]
__device__ __forceinline__ int q4_i8(float x, float a) {
  float t = x / a;  // IEEE div, matches numpy
  t = fminf(fmaxf(t, -8.0f), 7.0f);
  t = rintf(t);  // RNE, matches np.round
  return (int)t;
}

// ---- means of alpha_a1 (768) and alpha_a2 (3072), f64 accumulate ----------
__global__ void means_k(const float* __restrict__ v1, int n1,
                        const float* __restrict__ v2, int n2,
                        float* __restrict__ out) {
  const float* src = blockIdx.x ? v2 : v1;
  const int n = blockIdx.x ? n2 : n1;
  __shared__ double red[256];
  double s = 0.0;
  for (int i = threadIdx.x; i < n; i += 256) s += (double)src[i];
  red[threadIdx.x] = s;
  __syncthreads();
  for (int st = 128; st > 0; st >>= 1) {
    if (threadIdx.x < st) red[threadIdx.x] += red[threadIdx.x + st];
    __syncthreads();
  }
  if (threadIdx.x == 0) {
    float m = (float)(red[0] / (double)n);
    out[blockIdx.x] = m;
    if (blockIdx.x == 1) {
      out[2] = 1.0f / m;
      out[3] = 0.5f * (1.0f / m);
    }
  }
}

// ---- quantize activations x0 -> xq i8 -------------------------------------
__global__ void quant_x_k(const float* __restrict__ x,
                          unsigned* __restrict__ xq,
                          const float* __restrict__ means, int n4) {
  int i = blockIdx.x * blockDim.x + threadIdx.x;
  if (i >= n4) return;
  const float a = means[0];
  float4 v = ((const float4*)x)[i];
  unsigned u = (q4_i8(v.x, a) & 0xFF) | ((q4_i8(v.y, a) & 0xFF) << 8) |
               ((q4_i8(v.z, a) & 0xFF) << 16) | ((q4_i8(v.w, a) & 0xFF) << 24);
  xq[i] = u;
}

// ---- quantize weights [R][C] natural order, per-row alpha -----------------
__global__ void quant_w_k(const float* __restrict__ w,
                          const float* __restrict__ alpha,
                          unsigned* __restrict__ wq, int C, int n4) {
  int i = blockIdx.x * blockDim.x + threadIdx.x;
  if (i >= n4) return;
  int row = (i * 4) / C;
  const float a = alpha[row];
  float4 v = ((const float4*)w)[i];
  unsigned u = (q4_i8(v.x, a) & 0xFF) | ((q4_i8(v.y, a) & 0xFF) << 8) |
               ((q4_i8(v.z, a) & 0xFF) << 16) | ((q4_i8(v.w, a) & 0xFF) << 24);
  wq[i] = u;
}

// ---- GEMM1: C = A[M,K]*B[N,K]^T, 512t/8 waves, 128x128, BK=128 ------------
// T3+T4 pipeline: double-buffered LDS (64KB, 2 blocks/CU), counted vmcnt(4),
// raw s_barriers. K = NT*128 compile-time. Epilogue: dequant+bias -> gelu
// (A&S 7.1.26 erf) -> quant(a2) -> i8 byte stores.
template <int NT>
__global__ __launch_bounds__(512, 4) void gemm1_k(
    const signed char* __restrict__ A, const signed char* __restrict__ B,
    const float* __restrict__ alphaw, const float* __restrict__ bias,
    const float* __restrict__ means, signed char* __restrict__ out_b, int N) {
  constexpr int K = NT * 128;
  __shared__ __align__(16) signed char sA0[128 * 128];
  __shared__ __align__(16) signed char sB0[128 * 128];
  __shared__ __align__(16) signed char sA1[128 * 128];
  __shared__ __align__(16) signed char sB1[128 * 128];
  const int tid = threadIdx.x;
  const int w = tid >> 6;  // 0..7
  const int l = tid & 63;
  const int wm = w >> 1, wn = w & 1;
  const long bm0 = (long)blockIdx.y * 128;
  const long bn0 = (long)blockIdx.x * 128;

  i32x4 acc[2][4] = {};

  const int srow = l >> 3;                        // row-within-chunk 0..7
  const int scol = ((l & 7) * 16) ^ (srow << 4);  // pre-swizzled src col
  const int rsw = (l & 7) << 4;                   // read-side XOR

  const signed char* gA = A + (bm0 + w * 16 + srow) * (long)K + scol;
  const signed char* gB = B + (bn0 + w * 16 + srow) * (long)K + scol;

  auto STAGE = [&](signed char* dA, signed char* dB, int kt) {
#pragma unroll
    for (int i = 0; i < 2; ++i) {  // wave stages chunks 2w+i (A and B)
      gload_lds16(gA + (long)i * 8 * K + kt, dA + (w * 2 + i) * 1024);
      gload_lds16(gB + (long)i * 8 * K + kt, dB + (w * 2 + i) * 1024);
    }
  };
  auto COMPUTE = [&](const signed char* pA, const signed char* pB) {
#pragma unroll
    for (int kk = 0; kk < 2; ++kk) {
      const int kc = (kk * 64 + (l >> 4) * 16) ^ rsw;  // swizzled k-col
      i32x4 af[2], bg[4];
#pragma unroll
      for (int m = 0; m < 2; ++m)
        af[m] = *(const i32x4*)&pA[(wm * 32 + m * 16 + (l & 15)) * 128 + kc];
#pragma unroll
      for (int n = 0; n < 4; ++n)
        bg[n] = *(const i32x4*)&pB[(wn * 64 + n * 16 + (l & 15)) * 128 + kc];
#pragma unroll
      for (int m = 0; m < 2; ++m)
#pragma unroll
        for (int n = 0; n < 4; ++n)
          acc[m][n] = __builtin_amdgcn_mfma_i32_16x16x64_i8(af[m], bg[n],
                                                            acc[m][n], 0, 0, 0);
    }
  };

  // T3+T4: counted-vmcnt double-buffer. 4 gloads/thread per STAGE.
  STAGE(sA0, sB0, 0);
#pragma unroll
  for (int T = 0; T < NT; T += 2) {
    // phase A: prefetch tile T+1 -> buf1, compute tile T from buf0
    STAGE(sA1, sB1, (T + 1) * 128);          // T+1 <= NT-1 always (NT even)
    asm volatile("s_waitcnt vmcnt(4)" ::: "memory");  // buf0's 4 landed
    __builtin_amdgcn_s_barrier();
    COMPUTE(sA0, sB0);
    __builtin_amdgcn_s_barrier();            // readers of buf0 done
    // phase B: prefetch tile T+2 -> buf0, compute tile T+1 from buf1
    if (T + 2 < NT) {
      STAGE(sA0, sB0, (T + 2) * 128);
      asm volatile("s_waitcnt vmcnt(4)" ::: "memory");  // buf1's 4 landed
    } else {
      asm volatile("s_waitcnt vmcnt(0)" ::: "memory");  // drain final tile
    }
    __builtin_amdgcn_s_barrier();
    COMPUTE(sA1, sB1);
    __builtin_amdgcn_s_barrier();            // readers of buf1 done
  }

  const float a1 = means[0];
  const float half_inv_a2 = means[3];

  float awa1[4], bsc[4];
  const int cc0 = (int)bn0 + wn * 64 + (l & 15);
#pragma unroll
  for (int n = 0; n < 4; ++n) {
    awa1[n] = alphaw[cc0 + n * 16] * a1;
    bsc[n] = bias[cc0 + n * 16];
  }

  const int r0 = (int)bm0 + wm * 32 + (l >> 4) * 4;

#pragma unroll
  for (int m = 0; m < 2; ++m) {
#pragma unroll
    for (int rg = 0; rg < 4; ++rg) {
      const int r = r0 + m * 16 + rg;
      signed char* prow = out_b + (size_t)r * N + cc0;
#pragma unroll
      for (int n = 0; n < 4; ++n) {
        const float f = (float)acc[m][n][rg];  // exact: |acc| < 2^18
        const float t = fmaf(f, awa1[n], bsc[n]);
        // exact-formula GELU via A&S 7.1.26 erf (|err|<=1.5e-7), lean ops:
        const float x = t * 0.70710678118654752f;
        const float den = fmaf(0.3275911f, fabsf(x), 1.0f);  // abs = free mod
        const float rr = __builtin_amdgcn_rcpf(den);
        float p = fmaf(rr, 1.061405429f, -1.453152027f);
        p = fmaf(rr, p, 1.421413741f);
        p = fmaf(rr, p, -0.284496736f);
        p = fmaf(rr, p, 0.254829592f);
        const float q = p * rr;
        const float e = __expf(-(x * x));
        float er = fmaf(-q, e, 1.0f);
        er = copysignf(er, x);                 // v_bfi
        const float g2 = fmaf(er, t, t);       // t*(1+er), 1 ulp equiv
        float qv = g2 * half_inv_a2;
        qv = __builtin_amdgcn_fmed3f(qv, -8.0f, 7.0f);  // clamp, 1 inst
        qv = rintf(qv);
        prow[n * 16] = (signed char)(int)qv;
      }
    }
  }
}

// ---- GEMM2: C = A[M,K]*B[N,K]^T, 512t/8 waves, 128x128, BK=128 ------------
// EXACT r6 proven config (43us, frozen). dequant(a2,alpha_w2)+bias -> f32.
__global__ __launch_bounds__(512, 6) void gemm2_k(
    const signed char* __restrict__ A, const signed char* __restrict__ B,
    const float* __restrict__ alphaw, const float* __restrict__ bias,
    const float* __restrict__ means, float* __restrict__ out_f, int N, int K) {
  __shared__ __align__(16) signed char sA[128 * 128];
  __shared__ __align__(16) signed char sB[128 * 128];
  const int tid = threadIdx.x;
  const int w = tid >> 6;  // 0..7
  const int l = tid & 63;
  const int wm = w >> 1, wn = w & 1;
  const long bm0 = (long)blockIdx.y * 128;
  const long bn0 = (long)blockIdx.x * 128;

  i32x4 acc[2][4] = {};

  const int srow = l >> 3;                        // row-within-chunk 0..7
  const int scol = ((l & 7) * 16) ^ (srow << 4);  // pre-swizzled src col
  const int rsw = (l & 7) << 4;                   // read-side XOR

  const signed char* gA = A + (bm0 + w * 16 + srow) * (long)K + scol;
  const signed char* gB = B + (bn0 + w * 16 + srow) * (long)K + scol;

  for (int kt = 0; kt < K; kt += 128) {
    __syncthreads();  // previous tile's LDS reads done
#pragma unroll
    for (int i = 0; i < 2; ++i) {  // wave stages chunks 2w+i (A and B)
      gload_lds16(gA + (long)i * 8 * K + kt, &sA[(w * 2 + i) * 1024]);
      gload_lds16(gB + (long)i * 8 * K + kt, &sB[(w * 2 + i) * 1024]);
    }
    __syncthreads();  // staging visible (compiler drains vmcnt)
#pragma unroll
    for (int kk = 0; kk < 2; ++kk) {
      const int kc = (kk * 64 + (l >> 4) * 16) ^ rsw;  // swizzled k-col
      i32x4 af[2], bg[4];
#pragma unroll
      for (int m = 0; m < 2; ++m)
        af[m] = *(const i32x4*)&sA[(wm * 32 + m * 16 + (l & 15)) * 128 + kc];
#pragma unroll
      for (int n = 0; n < 4; ++n)
        bg[n] = *(const i32x4*)&sB[(wn * 64 + n * 16 + (l & 15)) * 128 + kc];
#pragma unroll
      for (int m = 0; m < 2; ++m)
#pragma unroll
        for (int n = 0; n < 4; ++n)
          acc[m][n] = __builtin_amdgcn_mfma_i32_16x16x64_i8(af[m], bg[n],
                                                            acc[m][n], 0, 0, 0);
    }
  }

  const float a2 = means[1];

  float awc[4], bsc[4];
  const int cc0 = (int)bn0 + wn * 64 + (l & 15);
#pragma unroll
  for (int n = 0; n < 4; ++n) {
    awc[n] = alphaw[cc0 + n * 16];
    bsc[n] = bias[cc0 + n * 16];
  }

  const int r0 = (int)bm0 + wm * 32 + (l >> 4) * 4;

#pragma unroll
  for (int m = 0; m < 2; ++m) {
#pragma unroll
    for (int rg = 0; rg < 4; ++rg) {
      const int r = r0 + m * 16 + rg;
      float* prow = out_f + (size_t)r * N + cc0;
#pragma unroll
      for (int n = 0; n < 4; ++n) {
        const float f = (float)acc[m][n][rg];
        // bit-exact numpy chain: ((x*aw)*a2) + b, no FMA contraction
        float t = __fmul_rn(f, awc[n]);
        t = __fmul_rn(t, a2);
        t = __fadd_rn(t, bsc[n]);
        prow[n * 16] = t;
      }
    }
  }
}

extern "C" void kernel_launch(void* const* d_in, const int* in_sizes, int n_in,
                              void* d_out, int out_size, void* d_ws,
                              size_t ws_size, hipStream_t stream) {
  const float* x0 = (const float*)d_in[0];
  const float* w1 = (const float*)d_in[1];
  const float* b1 = (const float*)d_in[2];
  const float* aw1 = (const float*)d_in[3];
  const float* aa1 = (const float*)d_in[4];
  const float* w2 = (const float*)d_in[5];
  const float* b2 = (const float*)d_in[6];
  const float* aw2 = (const float*)d_in[7];
  const float* aa2 = (const float*)d_in[8];

  char* ws = (char*)d_ws;
  float* means = (float*)ws;
  signed char* xq = (signed char*)(ws + 256);
  signed char* wq1 = (signed char*)(ws + 12583168);
  signed char* wq2 = (signed char*)(ws + 14942464);
  signed char* hq = (signed char*)(ws + 17301760);

  // 1) means of alpha_a1 / alpha_a2 (+ 1/a2, 0.5/a2)
  means_k<<<2, 256, 0, stream>>>(aa1, 768, aa2, 3072, means);
  // 2) quantize activations and weights to i8 (natural layouts)
  quant_x_k<<<12288, 256, 0, stream>>>(x0, (unsigned*)xq, means, 3145728);
  quant_w_k<<<2304, 256, 0, stream>>>(w1, aw1, (unsigned*)wq1, 768, 589824);
  quant_w_k<<<2304, 256, 0, stream>>>(w2, aw2, (unsigned*)wq2, 3072, 589824);
  // 3) GEMM1 [16384,768]x[3072,768]^T + gelu + requant -> hq (i8)
  //    T3+T4 counted-vmcnt pipeline, K=768 compile-time (NT=6)
  dim3 g1(24, 128);
  gemm1_k<6><<<g1, 512, 0, stream>>>(xq, wq1, aw1, b1, means, hq, 3072);
  // 4) GEMM2 [16384,3072]x[768,3072]^T + bias -> f32 out (frozen r6 config)
  dim3 g2(6, 128);
  gemm2_k<<<g2, 512, 0, stream>>>(hq, wq2, aw2, b2, means, (float*)d_out, 768,
                                  3072);
}